// Round 5
// baseline (261.173 us; speedup 1.0000x reference)
//
#include <hip/hip_runtime.h>
#include <hip/hip_bf16.h>
#include <stdint.h>

#define BB 8
#define CC 512
#define SS 1024
#define NH 8
#define DK 64
#define MM (BB*SS)      // 8192 rows
#define PQ 72           // P_lds pitch (elems): 144B rows, 16B-aligned

typedef __attribute__((ext_vector_type(8))) short bf16x8;
typedef __attribute__((ext_vector_type(4))) float f32x4;

__device__ inline float b2f(unsigned short u) {
    union { unsigned int i; float f; } x; x.i = ((unsigned int)u) << 16; return x.f;
}
__device__ inline unsigned short f2b(float f) {
    union { float f; unsigned int i; } x; x.f = f;
    unsigned int r = (x.i + 0x7FFFu + ((x.i >> 16) & 1u)) >> 16;
    return (unsigned short)r;
}
__device__ inline unsigned int cvtpk(float lo, float hi) {
    unsigned int r;
    asm("v_cvt_pk_bf16_f32 %0, %1, %2" : "=v"(r) : "v"(lo), "v"(hi));
    return r;
}
__device__ inline f32x4 mfma16(bf16x8 a, bf16x8 b, f32x4 c) {
    return __builtin_amdgcn_mfma_f32_16x16x32_bf16(a, b, c, 0, 0, 0);
}
__device__ __forceinline__ void gload16(const void* g, void* l) {
    __builtin_amdgcn_global_load_lds(
        (const __attribute__((address_space(1))) void*)g,
        (__attribute__((address_space(3))) void*)l, 16, 0, 0);
}

// ---------------- weight transpose + bf16 cast: w[K][N] -> wT[N][K], 16B stores ------
__global__ void __launch_bounds__(256) wtrans_kernel(const float* __restrict__ wq,
                                                     const float* __restrict__ wk,
                                                     const float* __restrict__ wv,
                                                     const float* __restrict__ wo,
                                                     unsigned short* __restrict__ wT) {
    __shared__ float lds[64][65];
    const float* w = (blockIdx.z == 0) ? wq : (blockIdx.z == 1) ? wk : (blockIdx.z == 2) ? wv : wo;
    unsigned short* o = wT + (size_t)blockIdx.z * (512 * 512);
    const int n0 = blockIdx.x * 64, k0 = blockIdx.y * 64;
    const int t = threadIdx.x;
    {
        const int nl = (t & 15) * 4, kr = t >> 4;
#pragma unroll
        for (int i = 0; i < 4; ++i) {
            float4 v = *(const float4*)(w + (size_t)(k0 + kr + i * 16) * 512 + n0 + nl);
            lds[kr + i * 16][nl] = v.x; lds[kr + i * 16][nl + 1] = v.y;
            lds[kr + i * 16][nl + 2] = v.z; lds[kr + i * 16][nl + 3] = v.w;
        }
    }
    __syncthreads();
    {
        const int k8 = (t & 7) * 8, nr = t >> 3;
#pragma unroll
        for (int ii = 0; ii < 2; ++ii) {
            int n = nr + ii * 32;
            unsigned short pk[8];
#pragma unroll
            for (int e = 0; e < 8; ++e) pk[e] = f2b(lds[k8 + e][n]);
            *(uint4*)&o[(size_t)(n0 + n) * 512 + k0 + k8] = *(uint4*)pk;
        }
    }
}

// ---------------- per-(b,s) LayerNorm stats: mean, rstd (float4-coalesced) ----------
__global__ void __launch_bounds__(256) stats_kernel(const float* __restrict__ x,
                                                    float2* __restrict__ stats) {
    __shared__ float2 red[16][64];
    const int b = blockIdx.y, s0 = blockIdx.x * 64;
    const int sl = (threadIdx.x & 15) * 4, cg = threadIdx.x >> 4;   // 16 lanes x float4
    float sum[4] = {0.f, 0.f, 0.f, 0.f}, sq[4] = {0.f, 0.f, 0.f, 0.f};
    const float* xp = x + ((size_t)b * 512 + cg * 32) * 1024 + s0 + sl;
#pragma unroll 4
    for (int i = 0; i < 32; ++i) {
        float4 v = *(const float4*)(xp + (size_t)i * 1024);
        sum[0] += v.x; sq[0] += v.x * v.x;
        sum[1] += v.y; sq[1] += v.y * v.y;
        sum[2] += v.z; sq[2] += v.z * v.z;
        sum[3] += v.w; sq[3] += v.w * v.w;
    }
#pragma unroll
    for (int e = 0; e < 4; ++e) red[cg][sl + e] = make_float2(sum[e], sq[e]);
    __syncthreads();
    if (threadIdx.x < 64) {
        float s = 0.f, q = 0.f;
#pragma unroll
        for (int c = 0; c < 16; ++c) { s += red[c][threadIdx.x].x; q += red[c][threadIdx.x].y; }
        float mean = s * (1.f / 512.f);
        float var = q * (1.f / 512.f) - mean * mean;
        stats[b * 1024 + s0 + threadIdx.x] = make_float2(mean, rsqrtf(var + 1e-5f));
    }
}

// ---------------- fused transpose + LN: x fp32 [B][C][S] -> xt, tn bf16 [B*S][C] -----
__global__ void __launch_bounds__(256) xln_kernel(const float* __restrict__ x,
                                                  const float2* __restrict__ stats,
                                                  const float* __restrict__ g,
                                                  const float* __restrict__ bta,
                                                  unsigned short* __restrict__ xt,
                                                  unsigned short* __restrict__ tn) {
    __shared__ float lds[64][65];
    const int s0 = blockIdx.x * 64, c0 = blockIdx.y * 64, b = blockIdx.z;
    const int t = threadIdx.x;
    {
        const int sl = (t & 15) * 4, cr = t >> 4;
#pragma unroll
        for (int i = 0; i < 4; ++i) {
            float4 v = *(const float4*)(x + ((size_t)b * 512 + c0 + cr + i * 16) * 1024 + s0 + sl);
            lds[cr + i * 16][sl] = v.x; lds[cr + i * 16][sl + 1] = v.y;
            lds[cr + i * 16][sl + 2] = v.z; lds[cr + i * 16][sl + 3] = v.w;
        }
    }
    __syncthreads();
    {
        const int c8 = (t & 7) * 8, sr = t >> 3;
        float gg[8], bb[8];
        {
            float4 g0 = *(const float4*)(g + c0 + c8), g1 = *(const float4*)(g + c0 + c8 + 4);
            float4 b0 = *(const float4*)(bta + c0 + c8), b1 = *(const float4*)(bta + c0 + c8 + 4);
            gg[0]=g0.x; gg[1]=g0.y; gg[2]=g0.z; gg[3]=g0.w; gg[4]=g1.x; gg[5]=g1.y; gg[6]=g1.z; gg[7]=g1.w;
            bb[0]=b0.x; bb[1]=b0.y; bb[2]=b0.z; bb[3]=b0.w; bb[4]=b1.x; bb[5]=b1.y; bb[6]=b1.z; bb[7]=b1.w;
        }
#pragma unroll
        for (int ii = 0; ii < 2; ++ii) {
            int s = sr + ii * 32;
            float2 st = stats[b * 1024 + s0 + s];
            unsigned short rawp[8], nrmp[8];
#pragma unroll
            for (int e = 0; e < 8; ++e) {
                float v = lds[c8 + e][s];
                rawp[e] = f2b(v);
                nrmp[e] = f2b((v - st.x) * st.y * gg[e] + bb[e]);
            }
            *(uint4*)&xt[((size_t)b * 1024 + s0 + s) * 512 + c0 + c8] = *(uint4*)rawp;
            *(uint4*)&tn[((size_t)b * 1024 + s0 + s) * 512 + c0 + c8] = *(uint4*)nrmp;
        }
    }
}

// ---------------- 128x128 GEMM core: global_load_lds + 2-phase double-buffer ---------
__device__ inline void gemm_tile(const unsigned short* __restrict__ A,
                                 const unsigned short* __restrict__ Bt,
                                 int m0, int n0,
                                 unsigned short (*A_lds)[128 * 64],
                                 unsigned short (*B_lds)[128 * 64],
                                 f32x4 acc[4][4]) {
    const int t = threadIdx.x;
    const int lane = t & 63, w = t >> 6;
    const int l15 = lane & 15, l4 = lane >> 4;
    const int wm = (w >> 1) * 64, wn = (w & 1) * 64;
    auto STAGE = [&](int bi, int kt) {
#pragma unroll
        for (int i = 0; i < 4; ++i) {
            int chunk = i * 256 + t;
            int row = chunk >> 3, kc = (chunk & 7) * 8;
            gload16(A + (size_t)(m0 + row) * 512 + kt * 64 + kc, &A_lds[bi][chunk * 8]);
            gload16(Bt + (size_t)(n0 + row) * 512 + kt * 64 + kc, &B_lds[bi][chunk * 8]);
        }
    };
    STAGE(0, 0);
    __syncthreads();
#pragma unroll 1
    for (int kt = 0; kt < 8; ++kt) {
        const int bi = kt & 1;
        if (kt < 7) STAGE(bi ^ 1, kt + 1);   // issue next tile; drains at barrier
#pragma unroll
        for (int kk = 0; kk < 2; ++kk) {
            bf16x8 af[4], bfr[4];
#pragma unroll
            for (int i = 0; i < 4; ++i)
                af[i] = *(const bf16x8*)&A_lds[bi][(wm + i * 16 + l15) * 64 + kk * 32 + l4 * 8];
#pragma unroll
            for (int j = 0; j < 4; ++j)
                bfr[j] = *(const bf16x8*)&B_lds[bi][(wn + j * 16 + l15) * 64 + kk * 32 + l4 * 8];
#pragma unroll
            for (int i = 0; i < 4; ++i)
#pragma unroll
                for (int j = 0; j < 4; ++j)
                    acc[i][j] = mfma16(af[i], bfr[j], acc[i][j]);
        }
        __syncthreads();   // vmcnt(0)+lgkmcnt(0): next tile resident, reads done
    }
}

// ---------------- QKV projection GEMM; V written pre-transposed [b][h][d][s] --------
__global__ void __launch_bounds__(256) gemm_qkv_kernel(const unsigned short* __restrict__ tn,
                                                       const unsigned short* __restrict__ wT,
                                                       const float* __restrict__ bq,
                                                       const float* __restrict__ bk,
                                                       const float* __restrict__ bv,
                                                       unsigned short* __restrict__ outbase) {
    __shared__ alignas(16) unsigned short A_lds[2][128 * 64];
    __shared__ alignas(16) unsigned short B_lds[2][128 * 64];
    const int z = blockIdx.z;
    const unsigned short* Bt = wT + (size_t)z * (512 * 512);
    const float* bias = (z == 0) ? bq : (z == 1) ? bk : bv;
    const int m0 = blockIdx.x * 128, n0 = blockIdx.y * 128;
    f32x4 acc[4][4];
    const f32x4 z4 = {0.f, 0.f, 0.f, 0.f};
#pragma unroll
    for (int i = 0; i < 4; ++i)
#pragma unroll
        for (int j = 0; j < 4; ++j) acc[i][j] = z4;
    gemm_tile(tn, Bt, m0, n0, A_lds, B_lds, acc);
    const int lane = threadIdx.x & 63, w = threadIdx.x >> 6;
    const int l15 = lane & 15, l4 = lane >> 4;
    const int wm = (w >> 1) * 64, wn = (w & 1) * 64;
    if (z < 2) {
        unsigned short* out = outbase + (size_t)z * MM * 512;
#pragma unroll
        for (int i = 0; i < 4; ++i)
#pragma unroll
            for (int j = 0; j < 4; ++j) {
                int col = n0 + wn + j * 16 + l15;
                float bcol = bias[col];
#pragma unroll
                for (int r = 0; r < 4; ++r) {
                    int row = m0 + wm + i * 16 + l4 * 4 + r;
                    out[(size_t)row * 512 + col] = f2b(acc[i][j][r] + bcol);
                }
            }
    } else {
        // vt[(b*512 + col)*1024 + s], 4 consecutive s per lane -> 8B packed store
        unsigned short* vt = outbase + (size_t)2 * MM * 512;
#pragma unroll
        for (int i = 0; i < 4; ++i)
#pragma unroll
            for (int j = 0; j < 4; ++j) {
                int col = n0 + wn + j * 16 + l15;
                float bcol = bias[col];
                int rowb = m0 + wm + i * 16 + l4 * 4;
                int bi = rowb >> 10, s0 = rowb & 1023;
                uint2 pk;
                pk.x = (unsigned int)f2b(acc[i][j][0] + bcol) |
                       ((unsigned int)f2b(acc[i][j][1] + bcol) << 16);
                pk.y = (unsigned int)f2b(acc[i][j][2] + bcol) |
                       ((unsigned int)f2b(acc[i][j][3] + bcol) << 16);
                *(uint2*)&vt[((size_t)bi * 512 + col) * 1024 + s0] = pk;
            }
    }
}

// ---------------- flash attention v5: direct-from-L2 K/V fragments, NO barriers ------
// K/V per (b,h) = 256 KB, L2-resident (Common-mistake #7 / m169: staging is overhead).
// Each wave independent: 16 q rows (q=l15), K-next reg-prefetch, V hidden under softmax.
__global__ void __launch_bounds__(256) attn_kernel(const unsigned short* __restrict__ q,
                                                   const unsigned short* __restrict__ k,
                                                   const unsigned short* __restrict__ vt,
                                                   unsigned short* __restrict__ o) {
    __shared__ alignas(16) unsigned short Pl[4][16 * PQ];   // per-wave P [q][key]
    // XCD-bijective swizzle: 1024 blocks -> each XCD owns 128 contiguous wgids
    // so all 16 q-tiles of a (b,h) share one XCD's L2 copy of K/V.
    const int pid = blockIdx.x;
    const int wgid = (pid & 7) * 128 + (pid >> 3);
    const int qt = wgid & 15, h = (wgid >> 4) & 7, b = wgid >> 7;
    const int t = threadIdx.x, lane = t & 63, w = t >> 6;
    const int l15 = lane & 15, l4 = lane >> 4;

    // Q B-fragments, pre-scaled by log2(e)/sqrt(64): scores land in log2 units
    const float QSC = 0.125f * 1.44269504f;
    const int qrow = qt * 64 + w * 16 + l15;
    const unsigned short* qp = q + ((size_t)(b * SS + qrow)) * 512 + h * 64;
    bf16x8 qf[2];
#pragma unroll
    for (int kk = 0; kk < 2; ++kk) {
        bf16x8 tmp = *(const bf16x8*)(qp + kk * 32 + l4 * 8);
#pragma unroll
        for (int e = 0; e < 8; ++e)
            tmp[e] = (short)f2b(b2f((unsigned short)tmp[e]) * QSC);
        qf[kk] = tmp;
    }

    // per-lane fragment bases
    const unsigned short* kbase = k + ((size_t)(b * SS) + l15) * 512 + h * 64 + l4 * 8;
    const unsigned short* vbase = vt + ((size_t)(b * NH + h) * DK + l15) * SS + l4 * 8;

    float m_run = -1e30f, l_run = 0.f;   // per-lane (l partial over this lane's key subset)
    f32x4 acc_o[4];                       // acc_o[j][r] = O[q=l4*4+r][d=j*16+l15]
    const f32x4 z4 = {0.f, 0.f, 0.f, 0.f};
#pragma unroll
    for (int j = 0; j < 4; ++j) acc_o[j] = z4;

    // K fragments for tile 0
    bf16x8 kf[2][4];
#pragma unroll
    for (int kk = 0; kk < 2; ++kk)
#pragma unroll
        for (int j = 0; j < 4; ++j)
            kf[kk][j] = *(const bf16x8*)(kbase + (size_t)(j * 16) * 512 + kk * 32);

#pragma unroll 2
    for (int kt = 0; kt < 16; ++kt) {
        const int key0 = kt * 64;

        // V fragments for this tile — issued early, consumed after softmax
        bf16x8 vf[2][4];
#pragma unroll
        for (int kk = 0; kk < 2; ++kk)
#pragma unroll
            for (int j = 0; j < 4; ++j)
                vf[kk][j] = *(const bf16x8*)(vbase + (size_t)(j * 16) * SS + key0 + kk * 32);

        // S^T = K @ Q^T : sc[j][r] = S[key=j*16+l4*4+r][q=l15] (log2 units)
        f32x4 sc[4];
#pragma unroll
        for (int j = 0; j < 4; ++j) sc[j] = z4;
        __builtin_amdgcn_s_setprio(1);
#pragma unroll
        for (int kk = 0; kk < 2; ++kk)
#pragma unroll
            for (int j = 0; j < 4; ++j)
                sc[j] = mfma16(kf[kk][j], qf[kk], sc[j]);
        __builtin_amdgcn_s_setprio(0);

        // K fragments for next tile (latency hidden under softmax+PV)
        const int keyn = (kt < 15) ? key0 + 64 : key0;
        bf16x8 kn[2][4];
#pragma unroll
        for (int kk = 0; kk < 2; ++kk)
#pragma unroll
            for (int j = 0; j < 4; ++j)
                kn[kk][j] = *(const bf16x8*)(kbase + (size_t)(keyn + j * 16) * 512 + kk * 32);

        // per-lane partial max over this lane's 16 keys
        float mx = fmaxf(fmaxf(sc[0][0], sc[0][1]), fmaxf(sc[0][2], sc[0][3]));
#pragma unroll
        for (int j = 1; j < 4; ++j)
            mx = fmaxf(mx, fmaxf(fmaxf(sc[j][0], sc[j][1]), fmaxf(sc[j][2], sc[j][3])));

        // defer-max: rescale only if some lane's subset outgrew m by >8 (wave-uniform)
        if (!__all(mx - m_run <= 8.f)) {
            mx = fmaxf(mx, __shfl_xor(mx, 16));
            mx = fmaxf(mx, __shfl_xor(mx, 32));
            float mnew = fmaxf(m_run, mx);
            float scl = exp2f(m_run - mnew);
            m_run = mnew;
            l_run *= scl;
            float scl_r[4];
#pragma unroll
            for (int r = 0; r < 4; ++r) scl_r[r] = __shfl(scl, (l4 << 2) | r);
#pragma unroll
            for (int j = 0; j < 4; ++j)
#pragma unroll
                for (int r = 0; r < 4; ++r) acc_o[j][r] *= scl_r[r];
        }

        float p[4][4], lsum = 0.f;
#pragma unroll
        for (int j = 0; j < 4; ++j)
#pragma unroll
            for (int r = 0; r < 4; ++r) {
                p[j][r] = exp2f(sc[j][r] - m_run);
                lsum += p[j][r];
            }
        l_run += lsum;

        // write P[q=l15][key=j*16+l4*4 .. +3] as one b64 per j (wave-private, no sync)
#pragma unroll
        for (int j = 0; j < 4; ++j) {
            uint2 pk;
            pk.x = cvtpk(p[j][0], p[j][1]);
            pk.y = cvtpk(p[j][2], p[j][3]);
            *(uint2*)&Pl[w][l15 * PQ + j * 16 + l4 * 4] = pk;
        }

        // O += P @ V  (A = P[q][k] from wave-private LDS, B = V^T key-contiguous)
        __builtin_amdgcn_s_setprio(1);
#pragma unroll
        for (int kk = 0; kk < 2; ++kk) {
            bf16x8 pf = *(const bf16x8*)&Pl[w][l15 * PQ + kk * 32 + l4 * 8];
#pragma unroll
            for (int j = 0; j < 4; ++j)
                acc_o[j] = mfma16(pf, vf[kk][j], acc_o[j]);
        }
        __builtin_amdgcn_s_setprio(0);

#pragma unroll
        for (int kk = 0; kk < 2; ++kk)
#pragma unroll
            for (int j = 0; j < 4; ++j)
                kf[kk][j] = kn[kk][j];
    }

    // total l per q: sum the 4 per-lane partials, then broadcast to output rows
    float l_tot = l_run;
    l_tot += __shfl_xor(l_tot, 16);
    l_tot += __shfl_xor(l_tot, 32);
    float l_r[4];
#pragma unroll
    for (int r = 0; r < 4; ++r) l_r[r] = __shfl(l_tot, (l4 << 2) | r);

#pragma unroll
    for (int j = 0; j < 4; ++j)
#pragma unroll
        for (int r = 0; r < 4; ++r) {
            int row = qt * 64 + w * 16 + l4 * 4 + r;
            float val = acc_o[j][r] / l_r[r];
            o[((size_t)(b * SS + row)) * 512 + h * 64 + j * 16 + l15] = f2b(val);
        }
}

// ---------------- output projection + bias + residual (coalesced bf16 resid) --------
__global__ void __launch_bounds__(256) gemm_out_kernel(const unsigned short* __restrict__ ao,
                                                       const unsigned short* __restrict__ woT,
                                                       const float* __restrict__ bo,
                                                       const unsigned short* __restrict__ xt,
                                                       float* __restrict__ out) {
    __shared__ alignas(16) unsigned short A_lds[2][128 * 64];
    __shared__ alignas(16) unsigned short B_lds[2][128 * 64];
    const int m0 = blockIdx.x * 128, n0 = blockIdx.y * 128;
    f32x4 acc[4][4];
    const f32x4 z4 = {0.f, 0.f, 0.f, 0.f};
#pragma unroll
    for (int i = 0; i < 4; ++i)
#pragma unroll
        for (int j = 0; j < 4; ++j) acc[i][j] = z4;
    gemm_tile(ao, woT, m0, n0, A_lds, B_lds, acc);
    const int lane = threadIdx.x & 63, w = threadIdx.x >> 6;
    const int l15 = lane & 15, l4 = lane >> 4;
    const int wm = (w >> 1) * 64, wn = (w & 1) * 64;
#pragma unroll
    for (int i = 0; i < 4; ++i)
#pragma unroll
        for (int j = 0; j < 4; ++j) {
            int col = n0 + wn + j * 16 + l15;
            float bcol = bo[col];
#pragma unroll
            for (int r = 0; r < 4; ++r) {
                int row = m0 + wm + i * 16 + l4 * 4 + r;
                float resid = b2f(xt[(size_t)row * 512 + col]);
                out[(size_t)row * 512 + col] = acc[i][j][r] + bcol + resid;
            }
        }
}

extern "C" void kernel_launch(void* const* d_in, const int* in_sizes, int n_in,
                              void* d_out, int out_size, void* d_ws, size_t ws_size,
                              hipStream_t stream) {
    const float* x   = (const float*)d_in[0];
    const float* wq  = (const float*)d_in[1];
    const float* bq  = (const float*)d_in[2];
    const float* wk  = (const float*)d_in[3];
    const float* bk  = (const float*)d_in[4];
    const float* wv  = (const float*)d_in[5];
    const float* bv  = (const float*)d_in[6];
    const float* lng = (const float*)d_in[7];
    const float* lnb = (const float*)d_in[8];
    const float* wo  = (const float*)d_in[9];
    const float* bo  = (const float*)d_in[10];
    float* out = (float*)d_out;

    unsigned short* ws  = (unsigned short*)d_ws;
    const size_t M1 = (size_t)1024 * 1024;
    unsigned short* tn   = ws;               // 4M elems (8 MB); reused as ao after qkv
    unsigned short* qkvb = ws + 4 * M1;      // q @ +0, k @ +4M, vt @ +8M (24 MB)
    unsigned short* wT   = ws + 16 * M1;     // 1M elems (2 MB)
    unsigned short* xt   = ws + 17 * M1;     // 4M elems (8 MB)
    unsigned short* ao   = tn;
    // LN stats live in the qkv region (consumed by xln BEFORE gemm_qkv overwrites it)
    float2* stats = (float2*)qkvb;

    wtrans_kernel<<<dim3(8, 8, 4), 256, 0, stream>>>(wq, wk, wv, wo, wT);
    stats_kernel<<<dim3(16, 8), 256, 0, stream>>>(x, stats);
    xln_kernel<<<dim3(16, 8, 8), 256, 0, stream>>>(x, stats, lng, lnb, xt, tn);
    gemm_qkv_kernel<<<dim3(64, 4, 3), 256, 0, stream>>>(tn, wT, bq, bk, bv, qkvb);
    attn_kernel<<<1024, 256, 0, stream>>>(qkvb,
                                          qkvb + (size_t)MM * 512,
                                          qkvb + (size_t)2 * MM * 512,
                                          ao);
    gemm_out_kernel<<<dim3(64, 4), 256, 0, stream>>>(ao, wT + (size_t)3 * 512 * 512, bo, xt, out);
}

// Round 6
// 176.370 us; speedup vs baseline: 1.4808x; 1.4808x over previous
//
#include <hip/hip_runtime.h>
#include <hip/hip_bf16.h>
#include <stdint.h>

#define BB 8
#define CC 512
#define SS 1024
#define NH 8
#define DK 64
#define MM (BB*SS)      // 8192 rows
#define PQ 72           // P_lds pitch (elems): 144B rows, 16B-aligned

typedef __attribute__((ext_vector_type(8))) short bf16x8;
typedef __attribute__((ext_vector_type(4))) float f32x4;

__device__ inline float b2f(unsigned short u) {
    union { unsigned int i; float f; } x; x.i = ((unsigned int)u) << 16; return x.f;
}
__device__ inline unsigned short f2b(float f) {
    union { float f; unsigned int i; } x; x.f = f;
    unsigned int r = (x.i + 0x7FFFu + ((x.i >> 16) & 1u)) >> 16;
    return (unsigned short)r;
}
__device__ inline unsigned int cvtpk(float lo, float hi) {
    unsigned int r;
    asm("v_cvt_pk_bf16_f32 %0, %1, %2" : "=v"(r) : "v"(lo), "v"(hi));
    return r;
}
__device__ inline f32x4 mfma16(bf16x8 a, bf16x8 b, f32x4 c) {
    return __builtin_amdgcn_mfma_f32_16x16x32_bf16(a, b, c, 0, 0, 0);
}
__device__ __forceinline__ void gload16(const void* g, void* l) {
    __builtin_amdgcn_global_load_lds(
        (const __attribute__((address_space(1))) void*)g,
        (__attribute__((address_space(3))) void*)l, 16, 0, 0);
}

// ---------------- weight transpose + bf16 cast: w[K][N] -> wT[N][K], 16B stores ------
__global__ void __launch_bounds__(256) wtrans_kernel(const float* __restrict__ wq,
                                                     const float* __restrict__ wk,
                                                     const float* __restrict__ wv,
                                                     const float* __restrict__ wo,
                                                     unsigned short* __restrict__ wT) {
    __shared__ float lds[64][65];
    const float* w = (blockIdx.z == 0) ? wq : (blockIdx.z == 1) ? wk : (blockIdx.z == 2) ? wv : wo;
    unsigned short* o = wT + (size_t)blockIdx.z * (512 * 512);
    const int n0 = blockIdx.x * 64, k0 = blockIdx.y * 64;
    const int t = threadIdx.x;
    {
        const int nl = (t & 15) * 4, kr = t >> 4;
#pragma unroll
        for (int i = 0; i < 4; ++i) {
            float4 v = *(const float4*)(w + (size_t)(k0 + kr + i * 16) * 512 + n0 + nl);
            lds[kr + i * 16][nl] = v.x; lds[kr + i * 16][nl + 1] = v.y;
            lds[kr + i * 16][nl + 2] = v.z; lds[kr + i * 16][nl + 3] = v.w;
        }
    }
    __syncthreads();
    {
        const int k8 = (t & 7) * 8, nr = t >> 3;
#pragma unroll
        for (int ii = 0; ii < 2; ++ii) {
            int n = nr + ii * 32;
            unsigned short pk[8];
#pragma unroll
            for (int e = 0; e < 8; ++e) pk[e] = f2b(lds[k8 + e][n]);
            *(uint4*)&o[(size_t)(n0 + n) * 512 + k0 + k8] = *(uint4*)pk;
        }
    }
}

// ---------------- per-(b,s) LayerNorm stats: mean, rstd (float4-coalesced) ----------
__global__ void __launch_bounds__(256) stats_kernel(const float* __restrict__ x,
                                                    float2* __restrict__ stats) {
    __shared__ float2 red[16][64];
    const int b = blockIdx.y, s0 = blockIdx.x * 64;
    const int sl = (threadIdx.x & 15) * 4, cg = threadIdx.x >> 4;   // 16 lanes x float4
    float sum[4] = {0.f, 0.f, 0.f, 0.f}, sq[4] = {0.f, 0.f, 0.f, 0.f};
    const float* xp = x + ((size_t)b * 512 + cg * 32) * 1024 + s0 + sl;
#pragma unroll 4
    for (int i = 0; i < 32; ++i) {
        float4 v = *(const float4*)(xp + (size_t)i * 1024);
        sum[0] += v.x; sq[0] += v.x * v.x;
        sum[1] += v.y; sq[1] += v.y * v.y;
        sum[2] += v.z; sq[2] += v.z * v.z;
        sum[3] += v.w; sq[3] += v.w * v.w;
    }
#pragma unroll
    for (int e = 0; e < 4; ++e) red[cg][sl + e] = make_float2(sum[e], sq[e]);
    __syncthreads();
    if (threadIdx.x < 64) {
        float s = 0.f, q = 0.f;
#pragma unroll
        for (int c = 0; c < 16; ++c) { s += red[c][threadIdx.x].x; q += red[c][threadIdx.x].y; }
        float mean = s * (1.f / 512.f);
        float var = q * (1.f / 512.f) - mean * mean;
        stats[b * 1024 + s0 + threadIdx.x] = make_float2(mean, rsqrtf(var + 1e-5f));
    }
}

// ---------------- fused transpose + LN: x fp32 [B][C][S] -> xt, tn bf16 [B*S][C] -----
__global__ void __launch_bounds__(256) xln_kernel(const float* __restrict__ x,
                                                  const float2* __restrict__ stats,
                                                  const float* __restrict__ g,
                                                  const float* __restrict__ bta,
                                                  unsigned short* __restrict__ xt,
                                                  unsigned short* __restrict__ tn) {
    __shared__ float lds[64][65];
    const int s0 = blockIdx.x * 64, c0 = blockIdx.y * 64, b = blockIdx.z;
    const int t = threadIdx.x;
    {
        const int sl = (t & 15) * 4, cr = t >> 4;
#pragma unroll
        for (int i = 0; i < 4; ++i) {
            float4 v = *(const float4*)(x + ((size_t)b * 512 + c0 + cr + i * 16) * 1024 + s0 + sl);
            lds[cr + i * 16][sl] = v.x; lds[cr + i * 16][sl + 1] = v.y;
            lds[cr + i * 16][sl + 2] = v.z; lds[cr + i * 16][sl + 3] = v.w;
        }
    }
    __syncthreads();
    {
        const int c8 = (t & 7) * 8, sr = t >> 3;
        float gg[8], bb[8];
        {
            float4 g0 = *(const float4*)(g + c0 + c8), g1 = *(const float4*)(g + c0 + c8 + 4);
            float4 b0 = *(const float4*)(bta + c0 + c8), b1 = *(const float4*)(bta + c0 + c8 + 4);
            gg[0]=g0.x; gg[1]=g0.y; gg[2]=g0.z; gg[3]=g0.w; gg[4]=g1.x; gg[5]=g1.y; gg[6]=g1.z; gg[7]=g1.w;
            bb[0]=b0.x; bb[1]=b0.y; bb[2]=b0.z; bb[3]=b0.w; bb[4]=b1.x; bb[5]=b1.y; bb[6]=b1.z; bb[7]=b1.w;
        }
#pragma unroll
        for (int ii = 0; ii < 2; ++ii) {
            int s = sr + ii * 32;
            float2 st = stats[b * 1024 + s0 + s];
            unsigned short rawp[8], nrmp[8];
#pragma unroll
            for (int e = 0; e < 8; ++e) {
                float v = lds[c8 + e][s];
                rawp[e] = f2b(v);
                nrmp[e] = f2b((v - st.x) * st.y * gg[e] + bb[e]);
            }
            *(uint4*)&xt[((size_t)b * 1024 + s0 + s) * 512 + c0 + c8] = *(uint4*)rawp;
            *(uint4*)&tn[((size_t)b * 1024 + s0 + s) * 512 + c0 + c8] = *(uint4*)nrmp;
        }
    }
}

// ---------------- 128x128 GEMM core: global_load_lds + 2-phase double-buffer ---------
__device__ inline void gemm_tile(const unsigned short* __restrict__ A,
                                 const unsigned short* __restrict__ Bt,
                                 int m0, int n0,
                                 unsigned short (*A_lds)[128 * 64],
                                 unsigned short (*B_lds)[128 * 64],
                                 f32x4 acc[4][4]) {
    const int t = threadIdx.x;
    const int lane = t & 63, w = t >> 6;
    const int l15 = lane & 15, l4 = lane >> 4;
    const int wm = (w >> 1) * 64, wn = (w & 1) * 64;
    auto STAGE = [&](int bi, int kt) {
#pragma unroll
        for (int i = 0; i < 4; ++i) {
            int chunk = i * 256 + t;
            int row = chunk >> 3, kc = (chunk & 7) * 8;
            gload16(A + (size_t)(m0 + row) * 512 + kt * 64 + kc, &A_lds[bi][chunk * 8]);
            gload16(Bt + (size_t)(n0 + row) * 512 + kt * 64 + kc, &B_lds[bi][chunk * 8]);
        }
    };
    STAGE(0, 0);
    __syncthreads();
#pragma unroll 1
    for (int kt = 0; kt < 8; ++kt) {
        const int bi = kt & 1;
        if (kt < 7) STAGE(bi ^ 1, kt + 1);   // issue next tile; drains at barrier
#pragma unroll
        for (int kk = 0; kk < 2; ++kk) {
            bf16x8 af[4], bfr[4];
#pragma unroll
            for (int i = 0; i < 4; ++i)
                af[i] = *(const bf16x8*)&A_lds[bi][(wm + i * 16 + l15) * 64 + kk * 32 + l4 * 8];
#pragma unroll
            for (int j = 0; j < 4; ++j)
                bfr[j] = *(const bf16x8*)&B_lds[bi][(wn + j * 16 + l15) * 64 + kk * 32 + l4 * 8];
#pragma unroll
            for (int i = 0; i < 4; ++i)
#pragma unroll
                for (int j = 0; j < 4; ++j)
                    acc[i][j] = mfma16(af[i], bfr[j], acc[i][j]);
        }
        __syncthreads();   // vmcnt(0)+lgkmcnt(0): next tile resident, reads done
    }
}

// ---------------- QKV projection GEMM; V written pre-transposed [b][h][d][s] --------
__global__ void __launch_bounds__(256) gemm_qkv_kernel(const unsigned short* __restrict__ tn,
                                                       const unsigned short* __restrict__ wT,
                                                       const float* __restrict__ bq,
                                                       const float* __restrict__ bk,
                                                       const float* __restrict__ bv,
                                                       unsigned short* __restrict__ outbase) {
    __shared__ alignas(16) unsigned short A_lds[2][128 * 64];
    __shared__ alignas(16) unsigned short B_lds[2][128 * 64];
    const int z = blockIdx.z;
    const unsigned short* Bt = wT + (size_t)z * (512 * 512);
    const float* bias = (z == 0) ? bq : (z == 1) ? bk : bv;
    const int m0 = blockIdx.x * 128, n0 = blockIdx.y * 128;
    f32x4 acc[4][4];
    const f32x4 z4 = {0.f, 0.f, 0.f, 0.f};
#pragma unroll
    for (int i = 0; i < 4; ++i)
#pragma unroll
        for (int j = 0; j < 4; ++j) acc[i][j] = z4;
    gemm_tile(tn, Bt, m0, n0, A_lds, B_lds, acc);
    const int lane = threadIdx.x & 63, w = threadIdx.x >> 6;
    const int l15 = lane & 15, l4 = lane >> 4;
    const int wm = (w >> 1) * 64, wn = (w & 1) * 64;
    if (z < 2) {
        unsigned short* out = outbase + (size_t)z * MM * 512;
#pragma unroll
        for (int i = 0; i < 4; ++i)
#pragma unroll
            for (int j = 0; j < 4; ++j) {
                int col = n0 + wn + j * 16 + l15;
                float bcol = bias[col];
#pragma unroll
                for (int r = 0; r < 4; ++r) {
                    int row = m0 + wm + i * 16 + l4 * 4 + r;
                    out[(size_t)row * 512 + col] = f2b(acc[i][j][r] + bcol);
                }
            }
    } else {
        // vt[(b*512 + col)*1024 + s], 4 consecutive s per lane -> 8B packed store
        unsigned short* vt = outbase + (size_t)2 * MM * 512;
#pragma unroll
        for (int i = 0; i < 4; ++i)
#pragma unroll
            for (int j = 0; j < 4; ++j) {
                int col = n0 + wn + j * 16 + l15;
                float bcol = bias[col];
                int rowb = m0 + wm + i * 16 + l4 * 4;
                int bi = rowb >> 10, s0 = rowb & 1023;
                uint2 pk;
                pk.x = (unsigned int)f2b(acc[i][j][0] + bcol) |
                       ((unsigned int)f2b(acc[i][j][1] + bcol) << 16);
                pk.y = (unsigned int)f2b(acc[i][j][2] + bcol) |
                       ((unsigned int)f2b(acc[i][j][3] + bcol) << 16);
                *(uint2*)&vt[((size_t)bi * 512 + col) * 1024 + s0] = pk;
            }
    }
}

// ---------------- flash attention v6: 8-wave QBLK=128, LDS-staged K/V, XCD-grouped ---
// Per wave: 16 q rows (q=l15). S^T = K @ Q^T; in-register softmax (exp2 units).
// One gload16 K + one V per thread per tile, pointer-incremented (minimal addr VALU).
__global__ void __launch_bounds__(512) attn_kernel(const unsigned short* __restrict__ q,
                                                   const unsigned short* __restrict__ k,
                                                   const unsigned short* __restrict__ vt,
                                                   unsigned short* __restrict__ o) {
    __shared__ alignas(16) unsigned short Kl[2][64 * 64];   // [key][d], source-swizzled
    __shared__ alignas(16) unsigned short Vl[2][64 * 64];   // [d][key], source-swizzled
    __shared__ alignas(16) unsigned short Pl[8][16 * PQ];   // per-wave P [q][key]
    // XCD grouping: xcd = pid&7 owns 8 (b,h) groups x 8 q-tiles (K/V 2MB < 4MB L2)
    const int pid = blockIdx.x;
    const int g = (pid >> 6) * 8 + (pid & 7);    // (b,h) group 0..63
    const int qt = (pid >> 3) & 7;               // q-tile 0..7 (128 rows each)
    const int b = g >> 3, h = g & 7;
    const int t = threadIdx.x, lane = t & 63, w = t >> 6;
    const int l15 = lane & 15, l4 = lane >> 4;

    // Q B-fragments, pre-scaled by log2(e)/sqrt(64): scores land in log2 units
    const float QSC = 0.125f * 1.44269504f;
    const int qrow = qt * 128 + w * 16 + l15;
    const unsigned short* qp = q + ((size_t)(b * SS + qrow)) * 512 + h * 64;
    bf16x8 qf[2];
#pragma unroll
    for (int kk = 0; kk < 2; ++kk) {
        bf16x8 tmp = *(const bf16x8*)(qp + kk * 32 + l4 * 8);
#pragma unroll
        for (int e = 0; e < 8; ++e)
            tmp[e] = (short)f2b(b2f((unsigned short)tmp[e]) * QSC);
        qf[kk] = tmp;
    }

    // staging pointers: thread owns one 16B chunk of K-tile and one of V-tile.
    // linear LDS dest, XOR-swizzled global source (involution on byte bits 4-6)
    const int srow = t >> 3;                       // 0..63 (key for K, d for V)
    const int scb = ((t & 7) * 16) ^ ((srow & 7) << 4);
    const char* kptr = (const char*)(k + ((size_t)(b * SS) + srow) * 512 + h * 64) + scb;
    const char* vptr = (const char*)(vt + ((size_t)(b * NH + h) * DK + srow) * SS) + scb;

    float m_run = -1e30f, l_run = 0.f;   // per-lane (l partial over this lane's key subset)
    f32x4 acc_o[4];                       // acc_o[j][r] = O[q=l4*4+r][d=j*16+l15]
    const f32x4 z4 = {0.f, 0.f, 0.f, 0.f};
#pragma unroll
    for (int j = 0; j < 4; ++j) acc_o[j] = z4;

    gload16(kptr, &Kl[0][t * 8]);
    gload16(vptr, &Vl[0][t * 8]);
    kptr += 64 * 512 * 2;   // next key tile: +64 rows
    vptr += 64 * 2;         // next key tile: +64 cols
    __syncthreads();

#pragma unroll 1
    for (int kt = 0; kt < 16; ++kt) {
        const int bi = kt & 1;
        if (kt < 15) {                        // issue next tile; drains at barrier
            gload16(kptr, &Kl[bi ^ 1][t * 8]);
            gload16(vptr, &Vl[bi ^ 1][t * 8]);
            kptr += 64 * 512 * 2;
            vptr += 64 * 2;
        }

        // S^T = K @ Q^T : sc[j][r] = S[key=j*16+l4*4+r][q=l15] (log2 units)
        f32x4 sc[4];
#pragma unroll
        for (int j = 0; j < 4; ++j) sc[j] = z4;
#pragma unroll
        for (int kk = 0; kk < 2; ++kk)
#pragma unroll
            for (int j = 0; j < 4; ++j) {
                int row = j * 16 + l15;
                int cb = (kk * 64 + l4 * 16) ^ ((row & 7) << 4);
                bf16x8 kf = *(const bf16x8*)((const char*)Kl[bi] + row * 128 + cb);
                sc[j] = mfma16(kf, qf[kk], sc[j]);
            }

        // per-lane max over this lane's 16 keys, reduce across the 4 l4 replicas
        float mx = fmaxf(fmaxf(sc[0][0], sc[0][1]), fmaxf(sc[0][2], sc[0][3]));
#pragma unroll
        for (int j = 1; j < 4; ++j)
            mx = fmaxf(mx, fmaxf(fmaxf(sc[j][0], sc[j][1]), fmaxf(sc[j][2], sc[j][3])));
        mx = fmaxf(mx, __shfl_xor(mx, 16));
        mx = fmaxf(mx, __shfl_xor(mx, 32));
        const float mnew = fmaxf(m_run, mx);
        const float scl = exp2f(m_run - mnew);
        m_run = mnew;

        float p[4][4], lsum = 0.f;
#pragma unroll
        for (int j = 0; j < 4; ++j)
#pragma unroll
            for (int r = 0; r < 4; ++r) {
                p[j][r] = exp2f(sc[j][r] - mnew);
                lsum += p[j][r];
            }
        l_run = l_run * scl + lsum;

        // write P[q=l15][key=j*16+l4*4 .. +3] as one b64 per j (wave-private, no sync)
#pragma unroll
        for (int j = 0; j < 4; ++j) {
            uint2 pk;
            pk.x = cvtpk(p[j][0], p[j][1]);
            pk.y = cvtpk(p[j][2], p[j][3]);
            *(uint2*)&Pl[w][l15 * PQ + j * 16 + l4 * 4] = pk;
        }

        // rescale O: row q=l4*4+r needs scl from lane q
        float scl_r[4];
#pragma unroll
        for (int r = 0; r < 4; ++r) scl_r[r] = __shfl(scl, (l4 << 2) | r);
#pragma unroll
        for (int j = 0; j < 4; ++j)
#pragma unroll
            for (int r = 0; r < 4; ++r) acc_o[j][r] *= scl_r[r];

        // O += P @ V  (A = P[q][k] from wave-private LDS, B = V^T key-contiguous)
#pragma unroll
        for (int kk = 0; kk < 2; ++kk) {
            bf16x8 pf = *(const bf16x8*)&Pl[w][l15 * PQ + kk * 32 + l4 * 8];
#pragma unroll
            for (int j = 0; j < 4; ++j) {
                int row = j * 16 + l15;
                int cb = (kk * 64 + l4 * 16) ^ ((row & 7) << 4);
                bf16x8 vf = *(const bf16x8*)((const char*)Vl[bi] + row * 128 + cb);
                acc_o[j] = mfma16(pf, vf, acc_o[j]);
            }
        }

        __syncthreads();   // vmcnt(0): next tile resident; reads of buf done
    }

    // total l per q: sum the 4 per-lane partials, then broadcast to output rows
    float l_tot = l_run;
    l_tot += __shfl_xor(l_tot, 16);
    l_tot += __shfl_xor(l_tot, 32);
    float l_r[4];
#pragma unroll
    for (int r = 0; r < 4; ++r) l_r[r] = __shfl(l_tot, (l4 << 2) | r);

#pragma unroll
    for (int j = 0; j < 4; ++j)
#pragma unroll
        for (int r = 0; r < 4; ++r) {
            int row = qt * 128 + w * 16 + l4 * 4 + r;
            float val = acc_o[j][r] / l_r[r];
            o[((size_t)(b * SS + row)) * 512 + h * 64 + j * 16 + l15] = f2b(val);
        }
}

// ---------------- output projection + bias + residual (coalesced bf16 resid) --------
__global__ void __launch_bounds__(256) gemm_out_kernel(const unsigned short* __restrict__ ao,
                                                       const unsigned short* __restrict__ woT,
                                                       const float* __restrict__ bo,
                                                       const unsigned short* __restrict__ xt,
                                                       float* __restrict__ out) {
    __shared__ alignas(16) unsigned short A_lds[2][128 * 64];
    __shared__ alignas(16) unsigned short B_lds[2][128 * 64];
    const int m0 = blockIdx.x * 128, n0 = blockIdx.y * 128;
    f32x4 acc[4][4];
    const f32x4 z4 = {0.f, 0.f, 0.f, 0.f};
#pragma unroll
    for (int i = 0; i < 4; ++i)
#pragma unroll
        for (int j = 0; j < 4; ++j) acc[i][j] = z4;
    gemm_tile(ao, woT, m0, n0, A_lds, B_lds, acc);
    const int lane = threadIdx.x & 63, w = threadIdx.x >> 6;
    const int l15 = lane & 15, l4 = lane >> 4;
    const int wm = (w >> 1) * 64, wn = (w & 1) * 64;
#pragma unroll
    for (int i = 0; i < 4; ++i)
#pragma unroll
        for (int j = 0; j < 4; ++j) {
            int col = n0 + wn + j * 16 + l15;
            float bcol = bo[col];
#pragma unroll
            for (int r = 0; r < 4; ++r) {
                int row = m0 + wm + i * 16 + l4 * 4 + r;
                float resid = b2f(xt[(size_t)row * 512 + col]);
                out[(size_t)row * 512 + col] = acc[i][j][r] + bcol + resid;
            }
        }
}

extern "C" void kernel_launch(void* const* d_in, const int* in_sizes, int n_in,
                              void* d_out, int out_size, void* d_ws, size_t ws_size,
                              hipStream_t stream) {
    const float* x   = (const float*)d_in[0];
    const float* wq  = (const float*)d_in[1];
    const float* bq  = (const float*)d_in[2];
    const float* wk  = (const float*)d_in[3];
    const float* bk  = (const float*)d_in[4];
    const float* wv  = (const float*)d_in[5];
    const float* bv  = (const float*)d_in[6];
    const float* lng = (const float*)d_in[7];
    const float* lnb = (const float*)d_in[8];
    const float* wo  = (const float*)d_in[9];
    const float* bo  = (const float*)d_in[10];
    float* out = (float*)d_out;

    unsigned short* ws  = (unsigned short*)d_ws;
    const size_t M1 = (size_t)1024 * 1024;
    unsigned short* tn   = ws;               // 4M elems (8 MB); reused as ao after qkv
    unsigned short* qkvb = ws + 4 * M1;      // q @ +0, k @ +4M, vt @ +8M (24 MB)
    unsigned short* wT   = ws + 16 * M1;     // 1M elems (2 MB)
    unsigned short* xt   = ws + 17 * M1;     // 4M elems (8 MB)
    unsigned short* ao   = tn;
    // LN stats live in the qkv region (consumed by xln BEFORE gemm_qkv overwrites it)
    float2* stats = (float2*)qkvb;

    wtrans_kernel<<<dim3(8, 8, 4), 256, 0, stream>>>(wq, wk, wv, wo, wT);
    stats_kernel<<<dim3(16, 8), 256, 0, stream>>>(x, stats);
    xln_kernel<<<dim3(16, 8, 8), 256, 0, stream>>>(x, stats, lng, lnb, xt, tn);
    gemm_qkv_kernel<<<dim3(64, 4, 3), 256, 0, stream>>>(tn, wT, bq, bk, bv, qkvb);
    attn_kernel<<<512, 512, 0, stream>>>(qkvb,
                                         qkvb + (size_t)MM * 512,
                                         qkvb + (size_t)2 * MM * 512,
                                         ao);
    gemm_out_kernel<<<dim3(64, 4), 256, 0, stream>>>(ao, wT + (size_t)3 * 512 * 512, bo, xt, out);
}